// Round 2
// baseline (600.612 us; speedup 1.0000x reference)
//
#include <hip/hip_runtime.h>
#include <cmath>

// Problem constants (from reference)
#define NVOC 100      // atom-type vocab
#define DIMN 200      // hidden dim
#define LDA  204      // padded LDS stride for [32][200] tiles (float4-aligned)
#define DPD  204      // DIM + NADD
#define LDM  36       // stride for 32x32 LDS matrices
#define NTOT 8192     // total atoms
// grid = 256 molecules (one block/CU), block = 256 threads

// NOTE: macro parameter must NOT be named `w` — it would capture the .w member.
#define FMA4(acc, s, wv) do { \
    (acc).x = fmaf((s),(wv).x,(acc).x); \
    (acc).y = fmaf((s),(wv).y,(acc).y); \
    (acc).z = fmaf((s),(wv).z,(acc).z); \
    (acc).w = fmaf((s),(wv).w,(acc).w); } while(0)

// hv[32][200] = src[32][200] @ W[200][200] + bias, per-thread 4x8 tile.
// src is LDS (b128 reads, few distinct addrs/wave -> broadcast-friendly);
// W streamed from global (L1/L2-resident: all 256 blocks read the same 160KB).
__device__ __forceinline__ void gemm_tile(const float* src,
                                          const float* __restrict__ W,
                                          const float* __restrict__ bias,
                                          int r0, int n0,
                                          float4 acc0[4], float4 acc1[4])
{
    const float4 b0 = *(const float4*)&bias[n0];
    const float4 b1 = *(const float4*)&bias[n0 + 4];
    #pragma unroll
    for (int i = 0; i < 4; ++i) { acc0[i] = b0; acc1[i] = b1; }

    #pragma unroll 2
    for (int k = 0; k < DIMN; k += 4) {
        const float4 a0 = *(const float4*)&src[(r0+0)*LDA + k];
        const float4 a1 = *(const float4*)&src[(r0+1)*LDA + k];
        const float4 a2 = *(const float4*)&src[(r0+2)*LDA + k];
        const float4 a3 = *(const float4*)&src[(r0+3)*LDA + k];
        const float* Wk = W + k*DIMN + n0;
        float4 w0, w1;
        w0 = *(const float4*)(Wk);          w1 = *(const float4*)(Wk + 4);
        FMA4(acc0[0],a0.x,w0); FMA4(acc1[0],a0.x,w1);
        FMA4(acc0[1],a1.x,w0); FMA4(acc1[1],a1.x,w1);
        FMA4(acc0[2],a2.x,w0); FMA4(acc1[2],a2.x,w1);
        FMA4(acc0[3],a3.x,w0); FMA4(acc1[3],a3.x,w1);
        w0 = *(const float4*)(Wk + DIMN);   w1 = *(const float4*)(Wk + DIMN + 4);
        FMA4(acc0[0],a0.y,w0); FMA4(acc1[0],a0.y,w1);
        FMA4(acc0[1],a1.y,w0); FMA4(acc1[1],a1.y,w1);
        FMA4(acc0[2],a2.y,w0); FMA4(acc1[2],a2.y,w1);
        FMA4(acc0[3],a3.y,w0); FMA4(acc1[3],a3.y,w1);
        w0 = *(const float4*)(Wk + 2*DIMN); w1 = *(const float4*)(Wk + 2*DIMN + 4);
        FMA4(acc0[0],a0.z,w0); FMA4(acc1[0],a0.z,w1);
        FMA4(acc0[1],a1.z,w0); FMA4(acc1[1],a1.z,w1);
        FMA4(acc0[2],a2.z,w0); FMA4(acc1[2],a2.z,w1);
        FMA4(acc0[3],a3.z,w0); FMA4(acc1[3],a3.z,w1);
        w0 = *(const float4*)(Wk + 3*DIMN); w1 = *(const float4*)(Wk + 3*DIMN + 4);
        FMA4(acc0[0],a0.w,w0); FMA4(acc1[0],a0.w,w1);
        FMA4(acc0[1],a1.w,w0); FMA4(acc1[1],a1.w,w1);
        FMA4(acc0[2],a2.w,w0); FMA4(acc1[2],a2.w,w1);
        FMA4(acc0[3],a3.w,w0); FMA4(acc1[3],a3.w,w1);
    }
}

__global__ __launch_bounds__(256, 1)
void mgnn_kernel(const int*   __restrict__ atoms,
                 const float* __restrict__ dist,
                 const float* __restrict__ adducts,
                 const float* __restrict__ embed,
                 const float* __restrict__ gamma_tab,
                 const float* __restrict__ Waw,
                 const float* __restrict__ Wab,
                 const float* __restrict__ Wow,
                 const float* __restrict__ Wob,
                 const float* __restrict__ Wpw,
                 const float* __restrict__ Wpb,
                 const float* __restrict__ Wprw,
                 const float* __restrict__ Wprb,
                 float* __restrict__ out)
{
    __shared__ float bufA[32*LDA];   // av  (26112 B)
    __shared__ float bufB[32*LDA];   // hv  (26112 B)
    __shared__ float d2s [32*LDM];   // squared intra-mol distances (4608 B)
    __shared__ float Mts [32*LDM];   // M transposed: Mts[j][r] = M[r][j] (4608 B)
    __shared__ float part[32*25];    // norm partials (3200 B)
    __shared__ float scale_s[32];
    __shared__ int   atom_s[32];
    // total static LDS = 64896 B < 160 KiB

    const int mol  = blockIdx.x;
    const int t    = threadIdx.x;
    const int base = mol * 32;
    const bool act = t < 200;
    const int rg = t / 25;           // 0..7  (act threads)
    const int cg = t % 25;           // 0..24
    const int r0 = rg * 4;
    const int n0 = cg * 8;

    // ---- init: atoms, intra-molecule d^2 block, av0 = embed[atoms] ----
    if (t < 32) atom_s[t] = atoms[base + t];
    {
        const int j  = t >> 3;            // 0..31
        const int c4 = (t & 7) * 4;       // 0,4,...,28
        const float4 dd = *(const float4*)&dist[(size_t)(base + j) * NTOT + base + c4];
        float4 q;
        q.x = dd.x*dd.x; q.y = dd.y*dd.y; q.z = dd.z*dd.z; q.w = dd.w*dd.w;
        *(float4*)&d2s[j*LDM + c4] = q;
    }
    for (int idx = t; idx < 32*50; idx += 256) {
        const int r  = idx / 50;
        const int c4 = (idx % 50) * 4;
        const int a  = atoms[base + r];
        *(float4*)&bufA[r*LDA + c4] = *(const float4*)&embed[a*DIMN + c4];
    }
    __syncthreads();

    // ---- 6 hidden layers: hv = relu(av@W+b); av = normalize(hv + M@hv) ----
    for (int l = 0; l < 6; ++l) {
        float4 acc0[4], acc1[4];
        if (act) {
            gemm_tile(bufA, Waw + l*DIMN*DIMN, Wab + l*DIMN, r0, n0, acc0, acc1);
            #pragma unroll
            for (int i = 0; i < 4; ++i) {
                float4 v0 = acc0[i], v1 = acc1[i];
                v0.x=fmaxf(v0.x,0.f); v0.y=fmaxf(v0.y,0.f); v0.z=fmaxf(v0.z,0.f); v0.w=fmaxf(v0.w,0.f);
                v1.x=fmaxf(v1.x,0.f); v1.y=fmaxf(v1.y,0.f); v1.z=fmaxf(v1.z,0.f); v1.w=fmaxf(v1.w,0.f);
                *(float4*)&bufB[(r0+i)*LDA + n0]     = v0;
                *(float4*)&bufB[(r0+i)*LDA + n0 + 4] = v1;
            }
        }
        {   // Mts[j][r] = exp(-g[j]*d2[r][j]) ; d2 symmetric so use d2[j][r]
            const int j  = t >> 3;
            const int rr = (t & 7) * 4;
            const float g = gamma_tab[l*NVOC + atom_s[j]];
            const float4 d = *(const float4*)&d2s[j*LDM + rr];
            float4 m;
            m.x = expf(-g*d.x); m.y = expf(-g*d.y); m.z = expf(-g*d.z); m.w = expf(-g*d.w);
            *(float4*)&Mts[j*LDM + rr] = m;
        }
        __syncthreads();

        if (act) {
            // av_new = hv + M@hv (block-local 32x32 propagation)
            #pragma unroll
            for (int i = 0; i < 4; ++i) {
                acc0[i] = *(const float4*)&bufB[(r0+i)*LDA + n0];
                acc1[i] = *(const float4*)&bufB[(r0+i)*LDA + n0 + 4];
            }
            #pragma unroll 4
            for (int j = 0; j < 32; ++j) {
                const float4 m  = *(const float4*)&Mts[j*LDM + r0];
                const float4 h0 = *(const float4*)&bufB[j*LDA + n0];
                const float4 h1 = *(const float4*)&bufB[j*LDA + n0 + 4];
                FMA4(acc0[0],m.x,h0); FMA4(acc1[0],m.x,h1);
                FMA4(acc0[1],m.y,h0); FMA4(acc1[1],m.y,h1);
                FMA4(acc0[2],m.z,h0); FMA4(acc1[2],m.z,h1);
                FMA4(acc0[3],m.w,h0); FMA4(acc1[3],m.w,h1);
            }
            // per-row sum-of-squares partials straight from registers
            #pragma unroll
            for (int i = 0; i < 4; ++i) {
                float s = acc0[i].x*acc0[i].x;
                s = fmaf(acc0[i].y,acc0[i].y,s);
                s = fmaf(acc0[i].z,acc0[i].z,s);
                s = fmaf(acc0[i].w,acc0[i].w,s);
                s = fmaf(acc1[i].x,acc1[i].x,s);
                s = fmaf(acc1[i].y,acc1[i].y,s);
                s = fmaf(acc1[i].z,acc1[i].z,s);
                s = fmaf(acc1[i].w,acc1[i].w,s);
                part[(r0+i)*25 + cg] = s;
            }
        }
        __syncthreads();
        if (t < 32) {
            float s = 0.f;
            #pragma unroll
            for (int c = 0; c < 25; ++c) s += part[t*25 + c];
            scale_s[t] = 1.0f / fmaxf(sqrtf(s), 1e-12f);
        }
        __syncthreads();
        if (act) {
            #pragma unroll
            for (int i = 0; i < 4; ++i) {
                const float sc = scale_s[r0+i];
                float4 v0 = acc0[i], v1 = acc1[i];
                v0.x*=sc; v0.y*=sc; v0.z*=sc; v0.w*=sc;
                v1.x*=sc; v1.y*=sc; v1.z*=sc; v1.w*=sc;
                *(float4*)&bufA[(r0+i)*LDA + n0]     = v0;
                *(float4*)&bufA[(r0+i)*LDA + n0 + 4] = v1;
            }
        }
        __syncthreads();
    }

    // ---- 3 out layers: av = relu(av@W+b), ping-pong A<->B ----
    float* cur = bufA;
    float* nxt = bufB;
    for (int l = 0; l < 3; ++l) {
        float4 acc0[4], acc1[4];
        if (act) {
            gemm_tile(cur, Wow + l*DIMN*DIMN, Wob + l*DIMN, r0, n0, acc0, acc1);
            #pragma unroll
            for (int i = 0; i < 4; ++i) {
                float4 v0 = acc0[i], v1 = acc1[i];
                v0.x=fmaxf(v0.x,0.f); v0.y=fmaxf(v0.y,0.f); v0.z=fmaxf(v0.z,0.f); v0.w=fmaxf(v0.w,0.f);
                v1.x=fmaxf(v1.x,0.f); v1.y=fmaxf(v1.y,0.f); v1.z=fmaxf(v1.z,0.f); v1.w=fmaxf(v1.w,0.f);
                *(float4*)&nxt[(r0+i)*LDA + n0]     = v0;
                *(float4*)&nxt[(r0+i)*LDA + n0 + 4] = v1;
            }
        }
        __syncthreads();
        float* tp = cur; cur = nxt; nxt = tp;
    }
    // final per-atom features now in `cur`

    // ---- molecule sum + adduct concat (d2s space reused for mv buffers) ----
    float* mv0 = d2s;         // 204 floats
    float* mv1 = d2s + 512;   // 204 floats
    if (t < DIMN) {
        float s = 0.f;
        #pragma unroll 4
        for (int r = 0; r < 32; ++r) s += cur[r*LDA + t];
        mv0[t] = s;
    } else if (t < DPD) {
        mv0[t] = adducts[mol*4 + (t - 200)];
    }
    __syncthreads();

    // ---- 3 pred layers on [204] vector ----
    float* pc = mv0;
    float* pn = mv1;
    for (int l = 0; l < 3; ++l) {
        if (t < DPD) {
            float acc = Wpb[l*DPD + t];
            const float* Wl = Wpw + l*DPD*DPD;
            #pragma unroll 4
            for (int k = 0; k < DPD; ++k)
                acc = fmaf(pc[k], Wl[k*DPD + t], acc);   // pc[k] = LDS broadcast, Wl coalesced
            pn[t] = fmaxf(acc, 0.f);
        }
        __syncthreads();
        float* tp = pc; pc = pn; pn = tp;
    }

    // ---- final property head: out = mv @ W_prop + b ----
    if (t < DPD) Mts[t] = pc[t] * Wprw[t];
    __syncthreads();
    if (t == 0) {
        float s = Wprb[0];
        for (int k = 0; k < DPD; ++k) s += Mts[k];
        out[mol] = s;
    }
}

extern "C" void kernel_launch(void* const* d_in, const int* in_sizes, int n_in,
                              void* d_out, int out_size, void* d_ws, size_t ws_size,
                              hipStream_t stream) {
    const int*   atoms   = (const int*)  d_in[0];
    const float* dist    = (const float*)d_in[1];
    const float* adducts = (const float*)d_in[2];
    const float* embed   = (const float*)d_in[3];
    const float* gamma_t = (const float*)d_in[4];
    const float* Waw     = (const float*)d_in[5];
    const float* Wab     = (const float*)d_in[6];
    const float* Wow     = (const float*)d_in[7];
    const float* Wob     = (const float*)d_in[8];
    const float* Wpw     = (const float*)d_in[9];
    const float* Wpb     = (const float*)d_in[10];
    const float* Wprw    = (const float*)d_in[11];
    const float* Wprb    = (const float*)d_in[12];
    (void)in_sizes; (void)n_in; (void)d_ws; (void)ws_size; (void)out_size;

    mgnn_kernel<<<dim3(256), dim3(256), 0, stream>>>(
        atoms, dist, adducts, embed, gamma_t,
        Waw, Wab, Wow, Wob, Wpw, Wpb, Wprw, Wprb,
        (float*)d_out);
}